// Round 1
// baseline (1879.251 us; speedup 1.0000x reference)
//
#include <hip/hip_runtime.h>
#include <math.h>

#define NTOK 131072
#define DIM  256
#define KEMB 1024
#define TM 64      // tokens per block
#define TK 64      // embeddings per K-chunk
#define DB 64      // d-chunk staged in LDS
#define SP 68      // padded LDS row stride (floats)

// ---------------- prep: embedding norms + zero counts ----------------
__global__ __launch_bounds__(64) void prep_kernel(const float* __restrict__ emb,
                                                  float* __restrict__ eNorm,
                                                  unsigned* __restrict__ counts) {
    const int k = blockIdx.x;          // one wave per embedding row
    const int lane = threadIdx.x;      // 0..63
    const float4 v = *reinterpret_cast<const float4*>(emb + (size_t)k * DIM + lane * 4);
    float s = v.x * v.x + v.y * v.y + v.z * v.z + v.w * v.w;
    #pragma unroll
    for (int m = 32; m; m >>= 1) s += __shfl_xor(s, m, 64);
    if (lane == 0) { eNorm[k] = s; counts[k] = 0u; }
}

// ---------------- main: distances + argmin + gather + histogram ----------------
__global__ __launch_bounds__(256) void vq_main(const float* __restrict__ x,
                                               const float* __restrict__ emb,
                                               const float* __restrict__ eNorm,
                                               unsigned* __restrict__ counts,
                                               float* __restrict__ out) {
    __shared__ float xs[TM][SP];
    __shared__ float es[TK][SP];
    __shared__ int   idx_s[TM];

    const int tid = threadIdx.x;
    const int tx  = tid & 15;          // embedding lane group
    const int ty  = tid >> 4;          // token lane group
    const int T0  = blockIdx.x * TM;

    float bestV[4];
    int   bestI[4];
    #pragma unroll
    for (int i = 0; i < 4; ++i) { bestV[i] = 3.4e38f; bestI[i] = 0; }

    for (int kc = 0; kc < KEMB; kc += TK) {
        float acc[4][4];
        #pragma unroll
        for (int i = 0; i < 4; ++i)
            #pragma unroll
            for (int j = 0; j < 4; ++j) acc[i][j] = 0.0f;

        for (int dc = 0; dc < DIM; dc += DB) {
            __syncthreads();   // protect LDS from previous iteration's readers
            // stage x tile (64x64) and emb tile (64x64): 4 float4 each per thread
            #pragma unroll
            for (int s = 0; s < 4; ++s) {
                const int f   = tid + s * 256;
                const int row = f >> 4;         // 16 float4 per row
                const int c4  = (f & 15) * 4;
                *reinterpret_cast<float4*>(&xs[row][c4]) =
                    *reinterpret_cast<const float4*>(&x[(size_t)(T0 + row) * DIM + dc + c4]);
                *reinterpret_cast<float4*>(&es[row][c4]) =
                    *reinterpret_cast<const float4*>(&emb[(size_t)(kc + row) * DIM + dc + c4]);
            }
            __syncthreads();

            #pragma unroll
            for (int d = 0; d < DB; d += 4) {
                float4 a[4], b[4];
                #pragma unroll
                for (int i = 0; i < 4; ++i)
                    a[i] = *reinterpret_cast<const float4*>(&xs[ty + 16 * i][d]);
                #pragma unroll
                for (int j = 0; j < 4; ++j)
                    b[j] = *reinterpret_cast<const float4*>(&es[tx + 16 * j][d]);
                #pragma unroll
                for (int i = 0; i < 4; ++i)
                    #pragma unroll
                    for (int j = 0; j < 4; ++j)
                        acc[i][j] += a[i].x * b[j].x + a[i].y * b[j].y
                                   + a[i].z * b[j].z + a[i].w * b[j].w;
            }
        }

        // fold this K-chunk into running best (dist = ||e||^2 - 2 x.e ; ||x||^2 dropped)
        #pragma unroll
        for (int j = 0; j < 4; ++j) {
            const int e = kc + tx + 16 * j;
            const float en = eNorm[e];
            #pragma unroll
            for (int i = 0; i < 4; ++i) {
                const float dist = en - 2.0f * acc[i][j];
                if (dist < bestV[i]) { bestV[i] = dist; bestI[i] = e; }
            }
        }
    }

    // reduce across the 16 tx lanes (same tokens), tie-break to lowest index
    #pragma unroll
    for (int m = 1; m <= 8; m <<= 1) {
        #pragma unroll
        for (int i = 0; i < 4; ++i) {
            const float ov = __shfl_xor(bestV[i], m, 64);
            const int   oi = __shfl_xor(bestI[i], m, 64);
            if (ov < bestV[i] || (ov == bestV[i] && oi < bestI[i])) {
                bestV[i] = ov; bestI[i] = oi;
            }
        }
    }
    if (tx == 0) {
        #pragma unroll
        for (int i = 0; i < 4; ++i) {
            idx_s[ty + 16 * i] = bestI[i];
            atomicAdd(&counts[bestI[i]], 1u);
        }
    }
    __syncthreads();

    // gather: out[token] = embeddings[idx]  (64 rows x 256 floats)
    #pragma unroll
    for (int s = 0; s < 16; ++s) {
        const int f   = tid + s * 256;   // f < 4096 float4s
        const int row = f >> 6;          // 64 float4 per row
        const int c4  = (f & 63) * 4;
        const int e   = idx_s[row];
        *reinterpret_cast<float4*>(&out[(size_t)(T0 + row) * DIM + c4]) =
            *reinterpret_cast<const float4*>(&emb[(size_t)e * DIM + c4]);
    }
}

// ---------------- perplexity ----------------
__global__ __launch_bounds__(256) void perp_kernel(const unsigned* __restrict__ counts,
                                                   float* __restrict__ out_perp) {
    __shared__ float red[256];
    const int tid = threadIdx.x;
    float s = 0.0f;
    for (int i = tid; i < KEMB; i += 256) {
        const float p = (float)counts[i] / (float)NTOK;
        s += p * logf(p + 1e-10f);
    }
    red[tid] = s;
    __syncthreads();
    for (int off = 128; off; off >>= 1) {
        if (tid < off) red[tid] += red[tid + off];
        __syncthreads();
    }
    if (tid == 0) *out_perp = expf(-red[0]);
}

extern "C" void kernel_launch(void* const* d_in, const int* in_sizes, int n_in,
                              void* d_out, int out_size, void* d_ws, size_t ws_size,
                              hipStream_t stream) {
    const float* x   = (const float*)d_in[0];
    const float* emb = (const float*)d_in[1];
    float* out = (float*)d_out;

    float*    eNorm  = (float*)d_ws;                 // 1024 floats
    unsigned* counts = (unsigned*)d_ws + 1024;       // 1024 uints

    prep_kernel<<<KEMB, 64, 0, stream>>>(emb, eNorm, counts);
    vq_main<<<NTOK / TM, 256, 0, stream>>>(x, emb, eNorm, counts, out);
    perp_kernel<<<1, 256, 0, stream>>>(counts, out + (size_t)NTOK * DIM);
}

// Round 3
// 597.156 us; speedup vs baseline: 3.1470x; 3.1470x over previous
//
#include <hip/hip_runtime.h>
#include <math.h>
#include <stdint.h>

#define NTOK 131072
#define DIM  256
#define KEMB 1024

typedef _Float16 f16x8 __attribute__((ext_vector_type(8)));
typedef float    f32x4 __attribute__((ext_vector_type(4)));

#define FLAG_CAP 65536
#define FLAG_THR 1026u   // ~0.5 distance units * 2048 quantization

static __device__ __forceinline__ unsigned umin32(unsigned a, unsigned b){ return a<b?a:b; }
static __device__ __forceinline__ unsigned umax32(unsigned a, unsigned b){ return a>b?a:b; }
static __device__ __forceinline__ unsigned long long umin64(unsigned long long a, unsigned long long b){ return a<b?a:b; }

// ---------------- prep: embedding norms, packed col consts, zero counters ----------------
__global__ __launch_bounds__(64) void prep_kernel(const float* __restrict__ emb,
                                                  float* __restrict__ eNorm,
                                                  float* __restrict__ eConst,
                                                  unsigned* __restrict__ counts,
                                                  unsigned* __restrict__ flagCnt) {
    const int k = blockIdx.x;
    const int lane = threadIdx.x;
    const float4 v = *reinterpret_cast<const float4*>(emb + (size_t)k * DIM + lane * 4);
    float s = v.x * v.x + v.y * v.y + v.z * v.z + v.w * v.w;
    #pragma unroll
    for (int m = 32; m; m >>= 1) s += __shfl_xor(s, m, 64);
    if (lane == 0) {
        eNorm[k]  = s;
        eConst[k] = (s + 512.0f) * 2048.0f;   // key = (dist+512)*2048 = eConst - 4096*dot
        counts[k] = 0u;
        if (k == 0) *flagCnt = 0u;
    }
}

// ---------------- main: fp16 MFMA distances + packed-key argmin/top2 ----------------
// Block: 256 threads = 4 waves, each wave owns 32 tokens (full K=256 fp16 A in regs).
// Loops 16 chunks of 64 embeddings staged fp16 in swizzled LDS.
__global__ __launch_bounds__(256, 2) void vq_main(const float* __restrict__ x,
                                                  const float* __restrict__ emb,
                                                  const float* __restrict__ eConst,
                                                  int* __restrict__ idxArr,
                                                  unsigned* __restrict__ flagCnt,
                                                  unsigned* __restrict__ flagList) {
    __shared__ _Float16 Elds[64 * 256];   // swizzled: 16B slot s -> s ^ (row&7)
    __shared__ float eCst_s[64];

    const int tid  = threadIdx.x;
    const int wv   = tid >> 6;
    const int lane = tid & 63;
    const int g    = lane >> 4;     // k-group 0..3
    const int c    = lane & 15;     // row/col within 16
    const int T0w  = blockIdx.x * 128 + wv * 32;

    // ---- A fragments: 2 row-frags x 8 k-frags, lane holds x[row][kk*32 + g*8 .. +7] (RNE cvt)
    f16x8 a[2][8];
    #pragma unroll
    for (int i = 0; i < 2; ++i) {
        const int row = T0w + i * 16 + c;
        const float* xr = x + (size_t)row * DIM + g * 8;
        #pragma unroll
        for (int kk = 0; kk < 8; ++kk) {
            const float4 f0 = *reinterpret_cast<const float4*>(xr + kk * 32);
            const float4 f1 = *reinterpret_cast<const float4*>(xr + kk * 32 + 4);
            a[i][kk] = (f16x8){(_Float16)f0.x, (_Float16)f0.y, (_Float16)f0.z, (_Float16)f0.w,
                               (_Float16)f1.x, (_Float16)f1.y, (_Float16)f1.z, (_Float16)f1.w};
        }
    }

    unsigned m1[8], m2[8];
    #pragma unroll
    for (int t = 0; t < 8; ++t) { m1[t] = 0xFFFFFFFFu; m2[t] = 0xFFFFFFFFu; }

    for (int ec = 0; ec < 16; ++ec) {
        __syncthreads();
        // stage 64x256 fp32 -> fp16 swizzled (perfectly coalesced global reads)
        #pragma unroll
        for (int i = 0; i < 16; ++i) {
            const int fi  = i * 256 + tid;       // float4 index in chunk (4096 total)
            const int row = fi >> 6;
            const int q4  = fi & 63;
            const float4 f = *reinterpret_cast<const float4*>(
                emb + (size_t)(ec * 64 + row) * DIM + q4 * 4);
            const auto p0 = __builtin_amdgcn_cvt_pkrtz(f.x, f.y);
            const auto p1 = __builtin_amdgcn_cvt_pkrtz(f.z, f.w);
            uint2 uv;
            uv.x = __builtin_bit_cast(unsigned, p0);
            uv.y = __builtin_bit_cast(unsigned, p1);
            const int s    = q4 >> 1;            // 16B slot 0..31
            const int hb   = (q4 & 1) * 4;
            const int hidx = row * 256 + (((s ^ (row & 7)) << 3) | hb);
            *reinterpret_cast<uint2*>(&Elds[hidx]) = uv;
        }
        if (tid < 64) eCst_s[tid] = eConst[ec * 64 + tid];
        __syncthreads();

        f32x4 acc[2][4];
        #pragma unroll
        for (int i = 0; i < 2; ++i)
            #pragma unroll
            for (int j = 0; j < 4; ++j) acc[i][j] = (f32x4){0.f, 0.f, 0.f, 0.f};

        #pragma unroll
        for (int kk = 0; kk < 8; ++kk) {
            f16x8 b[4];
            #pragma unroll
            for (int j = 0; j < 4; ++j) {
                const int row  = j * 16 + c;
                const int s    = kk * 4 + g;
                const int hidx = row * 256 + ((s ^ (row & 7)) << 3);
                b[j] = *reinterpret_cast<const f16x8*>(&Elds[hidx]);
            }
            #pragma unroll
            for (int i = 0; i < 2; ++i)
                #pragma unroll
                for (int j = 0; j < 4; ++j)
                    acc[i][j] = __builtin_amdgcn_mfma_f32_16x16x32_f16(a[i][kk], b[j], acc[i][j], 0, 0, 0);
        }

        // fold chunk into running top-2 packed keys
        #pragma unroll
        for (int j = 0; j < 4; ++j) {
            const float    cst    = eCst_s[j * 16 + c];
            const unsigned colIdx = (unsigned)(ec * 64 + j * 16 + c);
            #pragma unroll
            for (int i = 0; i < 2; ++i)
                #pragma unroll
                for (int e = 0; e < 4; ++e) {
                    const float    qf  = fmaf(acc[i][j][e], -4096.0f, cst);
                    const unsigned key = (((unsigned)qf) << 10) | colIdx;
                    const int t = i * 4 + e;
                    const unsigned lo = umin32(key, m1[t]);
                    const unsigned hi = umax32(key, m1[t]);
                    m1[t] = lo;
                    m2[t] = umin32(m2[t], hi);
                }
        }
    }

    // cross-column reduce within 16-lane groups (tokens live in rows, cols across lanes)
    #pragma unroll
    for (int off = 1; off < 16; off <<= 1) {
        #pragma unroll
        for (int t = 0; t < 8; ++t) {
            const unsigned o1 = __shfl_xor(m1[t], off, 64);
            const unsigned o2 = __shfl_xor(m2[t], off, 64);
            const unsigned nm2 = umin32(umin32(m2[t], o2), umax32(m1[t], o1));
            m1[t] = umin32(m1[t], o1);
            m2[t] = nm2;
        }
    }

    if (c == 0) {
        #pragma unroll
        for (int t = 0; t < 8; ++t) {
            const int row   = (t >> 2) * 16 + g * 4 + (t & 3);
            const int token = T0w + row;
            idxArr[token] = (int)(m1[t] & 1023u);
            if (((m2[t] >> 10) - (m1[t] >> 10)) < FLAG_THR) {
                const unsigned pos = atomicAdd(flagCnt, 1u);
                if (pos < FLAG_CAP) flagList[pos] = (unsigned)token;
            }
        }
    }
}

// ---------------- fixup: exact fp32 re-argmin for flagged tokens (batched 8/block) ----------------
__global__ __launch_bounds__(256) void fixup_kernel(const float* __restrict__ x,
                                                    const float* __restrict__ emb,
                                                    const float* __restrict__ eNorm,
                                                    const unsigned* __restrict__ flagCnt,
                                                    const unsigned* __restrict__ flagList,
                                                    int* __restrict__ idxArr) {
    __shared__ float xs[8][256];
    __shared__ unsigned long long red[4][8];
    const unsigned nf = umin32(*flagCnt, (unsigned)FLAG_CAP);
    const int tid  = threadIdx.x;
    const int lane = tid & 63;
    const int wv   = tid >> 6;

    for (unsigned base = blockIdx.x * 8u; base < nf; base += gridDim.x * 8u) {
        const unsigned B = umin32(8u, nf - base);
        __syncthreads();
        #pragma unroll
        for (int f = 0; f < 8; ++f) {
            const unsigned tok = flagList[base + (f < (int)B ? f : 0)];
            xs[f][tid] = x[(size_t)tok * DIM + tid];
        }
        __syncthreads();

        const int e0 = tid * 4;
        float acc[4][8];
        #pragma unroll
        for (int j = 0; j < 4; ++j)
            #pragma unroll
            for (int f = 0; f < 8; ++f) acc[j][f] = 0.0f;

        for (int k = 0; k < DIM; k += 4) {
            float4 ev[4];
            #pragma unroll
            for (int j = 0; j < 4; ++j)
                ev[j] = *reinterpret_cast<const float4*>(emb + (size_t)(e0 + j) * DIM + k);
            #pragma unroll
            for (int f = 0; f < 8; ++f) {
                const float4 xv = *reinterpret_cast<const float4*>(&xs[f][k]);
                #pragma unroll
                for (int j = 0; j < 4; ++j)
                    acc[j][f] += ev[j].x * xv.x + ev[j].y * xv.y + ev[j].z * xv.z + ev[j].w * xv.w;
            }
        }

        float en[4];
        #pragma unroll
        for (int j = 0; j < 4; ++j) en[j] = eNorm[e0 + j];

        #pragma unroll
        for (int f = 0; f < 8; ++f) {
            unsigned long long kb = 0xFFFFFFFFFFFFFFFFull;
            #pragma unroll
            for (int j = 0; j < 4; ++j) {
                const float d = en[j] - 2.0f * acc[j][f] + 512.0f;   // >0 always
                const unsigned long long key =
                    (((unsigned long long)__builtin_bit_cast(unsigned, d)) << 10) |
                    (unsigned long long)(e0 + j);
                kb = umin64(kb, key);
            }
            #pragma unroll
            for (int off = 1; off < 64; off <<= 1)
                kb = umin64(kb, __shfl_xor(kb, off, 64));
            if (lane == 0) red[wv][f] = kb;
        }
        __syncthreads();
        if (tid < 8) {
            unsigned long long m = umin64(umin64(red[0][tid], red[1][tid]),
                                          umin64(red[2][tid], red[3][tid]));
            if (tid < (int)B)
                idxArr[flagList[base + tid]] = (int)(m & 1023ull);
        }
    }
}

// ---------------- gather + histogram ----------------
__global__ __launch_bounds__(256) void gather_hist(const float* __restrict__ emb,
                                                   const int* __restrict__ idxArr,
                                                   unsigned* __restrict__ counts,
                                                   float* __restrict__ out) {
    __shared__ int idx_s[256];
    const int tid = threadIdx.x;
    const int T0  = blockIdx.x * 256;
    const int e   = idxArr[T0 + tid];
    idx_s[tid] = e;
    atomicAdd(&counts[e], 1u);
    __syncthreads();
    #pragma unroll 4
    for (int s = 0; s < 64; ++s) {
        const int fi  = s * 256 + tid;   // 16384 float4 per block
        const int row = fi >> 6;
        const int q4  = fi & 63;
        const int em  = idx_s[row];
        *reinterpret_cast<float4*>(out + (size_t)(T0 + row) * DIM + q4 * 4) =
            *reinterpret_cast<const float4*>(emb + (size_t)em * DIM + q4 * 4);
    }
}

// ---------------- perplexity ----------------
__global__ __launch_bounds__(256) void perp_kernel(const unsigned* __restrict__ counts,
                                                   float* __restrict__ out_perp) {
    __shared__ float red[256];
    const int tid = threadIdx.x;
    float s = 0.0f;
    for (int i = tid; i < KEMB; i += 256) {
        const float p = (float)counts[i] / (float)NTOK;
        s += p * logf(p + 1e-10f);
    }
    red[tid] = s;
    __syncthreads();
    for (int off = 128; off; off >>= 1) {
        if (tid < off) red[tid] += red[tid + off];
        __syncthreads();
    }
    if (tid == 0) *out_perp = expf(-red[0]);
}

extern "C" void kernel_launch(void* const* d_in, const int* in_sizes, int n_in,
                              void* d_out, int out_size, void* d_ws, size_t ws_size,
                              hipStream_t stream) {
    (void)in_sizes; (void)n_in; (void)out_size; (void)ws_size;
    const float* x   = (const float*)d_in[0];
    const float* emb = (const float*)d_in[1];
    float* out = (float*)d_out;

    char* ws = (char*)d_ws;
    float*    eNorm    = (float*)(ws);
    float*    eConst   = (float*)(ws + 4096);
    unsigned* counts   = (unsigned*)(ws + 8192);
    unsigned* flagCnt  = (unsigned*)(ws + 12288);
    unsigned* flagList = (unsigned*)(ws + 16384);
    int*      idxArr   = (int*)(ws + 16384 + FLAG_CAP * 4);

    prep_kernel<<<KEMB, 64, 0, stream>>>(emb, eNorm, eConst, counts, flagCnt);
    vq_main<<<NTOK / 128, 256, 0, stream>>>(x, emb, eConst, idxArr, flagCnt, flagList);
    fixup_kernel<<<256, 256, 0, stream>>>(x, emb, eNorm, flagCnt, flagList, idxArr);
    gather_hist<<<NTOK / 256, 256, 0, stream>>>(emb, idxArr, counts, out);
    perp_kernel<<<1, 256, 0, stream>>>(counts, out + (size_t)NTOK * DIM);
}

// Round 4
// 490.654 us; speedup vs baseline: 3.8301x; 1.2171x over previous
//
#include <hip/hip_runtime.h>
#include <math.h>
#include <stdint.h>

#define NTOK 131072
#define DIM  256
#define KEMB 1024

typedef _Float16 f16x8 __attribute__((ext_vector_type(8)));
typedef float    f32x4 __attribute__((ext_vector_type(4)));

#define FLAG_CAP 65536
#define FLAG_THR 1026u   // ~0.5 distance units * 2048 quantization

static __device__ __forceinline__ unsigned umin32(unsigned a, unsigned b){ return a<b?a:b; }
static __device__ __forceinline__ unsigned umax32(unsigned a, unsigned b){ return a>b?a:b; }
static __device__ __forceinline__ unsigned long long umin64(unsigned long long a, unsigned long long b){ return a<b?a:b; }

// ---------------- prep: embedding norms, packed col consts, zero counters ----------------
__global__ __launch_bounds__(64) void prep_kernel(const float* __restrict__ emb,
                                                  float* __restrict__ eNorm,
                                                  float* __restrict__ eConst,
                                                  unsigned* __restrict__ counts,
                                                  unsigned* __restrict__ flagCnt) {
    const int k = blockIdx.x;
    const int lane = threadIdx.x;
    const float4 v = *reinterpret_cast<const float4*>(emb + (size_t)k * DIM + lane * 4);
    float s = v.x * v.x + v.y * v.y + v.z * v.z + v.w * v.w;
    #pragma unroll
    for (int m = 32; m; m >>= 1) s += __shfl_xor(s, m, 64);
    if (lane == 0) {
        eNorm[k]  = s;
        eConst[k] = (s + 512.0f) * 2048.0f;   // key = (dist+512)*2048 = eConst - 4096*dot
        counts[k] = 0u;
        if (k == 0) *flagCnt = 0u;
    }
}

// ---------------- main: fp16 MFMA distances + packed-key argmin/top2 ----------------
__global__ __launch_bounds__(256, 2) void vq_main(const float* __restrict__ x,
                                                  const float* __restrict__ emb,
                                                  const float* __restrict__ eConst,
                                                  int* __restrict__ idxArr,
                                                  unsigned* __restrict__ flagCnt,
                                                  unsigned* __restrict__ flagList) {
    __shared__ _Float16 Elds[64 * 256];   // swizzled: 16B slot s -> s ^ (row&7)
    __shared__ float eCst_s[64];

    const int tid  = threadIdx.x;
    const int wv   = tid >> 6;
    const int lane = tid & 63;
    const int g    = lane >> 4;     // k-group 0..3
    const int c    = lane & 15;     // row/col within 16
    const int T0w  = blockIdx.x * 128 + wv * 32;

    // ---- A fragments: 2 row-frags x 8 k-frags, lane holds x[row][kk*32 + g*8 .. +7]
    f16x8 a[2][8];
    #pragma unroll
    for (int i = 0; i < 2; ++i) {
        const int row = T0w + i * 16 + c;
        const float* xr = x + (size_t)row * DIM + g * 8;
        #pragma unroll
        for (int kk = 0; kk < 8; ++kk) {
            const float4 f0 = *reinterpret_cast<const float4*>(xr + kk * 32);
            const float4 f1 = *reinterpret_cast<const float4*>(xr + kk * 32 + 4);
            a[i][kk] = (f16x8){(_Float16)f0.x, (_Float16)f0.y, (_Float16)f0.z, (_Float16)f0.w,
                               (_Float16)f1.x, (_Float16)f1.y, (_Float16)f1.z, (_Float16)f1.w};
        }
    }

    unsigned m1[8], m2[8];
    #pragma unroll
    for (int t = 0; t < 8; ++t) { m1[t] = 0xFFFFFFFFu; m2[t] = 0xFFFFFFFFu; }

    for (int ec = 0; ec < 16; ++ec) {
        __syncthreads();
        // stage 64x256 fp32 -> fp16 swizzled (coalesced global reads)
        #pragma unroll
        for (int i = 0; i < 16; ++i) {
            const int fi  = i * 256 + tid;       // float4 index in chunk (4096 total)
            const int row = fi >> 6;
            const int q4  = fi & 63;
            const float4 f = *reinterpret_cast<const float4*>(
                emb + (size_t)(ec * 64 + row) * DIM + q4 * 4);
            const auto p0 = __builtin_amdgcn_cvt_pkrtz(f.x, f.y);
            const auto p1 = __builtin_amdgcn_cvt_pkrtz(f.z, f.w);
            uint2 uv;
            uv.x = __builtin_bit_cast(unsigned, p0);
            uv.y = __builtin_bit_cast(unsigned, p1);
            const int s    = q4 >> 1;            // 16B slot 0..31
            const int hb   = (q4 & 1) * 4;
            const int hidx = row * 256 + (((s ^ (row & 7)) << 3) | hb);
            *reinterpret_cast<uint2*>(&Elds[hidx]) = uv;
        }
        if (tid < 64) eCst_s[tid] = eConst[ec * 64 + tid];
        __syncthreads();

        f32x4 acc[2][4];
        #pragma unroll
        for (int i = 0; i < 2; ++i)
            #pragma unroll
            for (int j = 0; j < 4; ++j) acc[i][j] = (f32x4){0.f, 0.f, 0.f, 0.f};

        #pragma unroll
        for (int kk = 0; kk < 8; ++kk) {
            f16x8 b[4];
            #pragma unroll
            for (int j = 0; j < 4; ++j) {
                const int row  = j * 16 + c;
                const int s    = kk * 4 + g;
                const int hidx = row * 256 + ((s ^ (row & 7)) << 3);
                b[j] = *reinterpret_cast<const f16x8*>(&Elds[hidx]);
            }
            #pragma unroll
            for (int i = 0; i < 2; ++i)
                #pragma unroll
                for (int j = 0; j < 4; ++j)
                    acc[i][j] = __builtin_amdgcn_mfma_f32_16x16x32_f16(a[i][kk], b[j], acc[i][j], 0, 0, 0);
        }

        // fold chunk into running top-2 packed keys
        #pragma unroll
        for (int j = 0; j < 4; ++j) {
            const float    cst    = eCst_s[j * 16 + c];
            const unsigned colIdx = (unsigned)(ec * 64 + j * 16 + c);
            #pragma unroll
            for (int i = 0; i < 2; ++i)
                #pragma unroll
                for (int e = 0; e < 4; ++e) {
                    const float    qf  = fmaf(acc[i][j][e], -4096.0f, cst);
                    const unsigned key = (((unsigned)qf) << 10) | colIdx;
                    const int t = i * 4 + e;
                    const unsigned lo = umin32(key, m1[t]);
                    const unsigned hi = umax32(key, m1[t]);
                    m1[t] = lo;
                    m2[t] = umin32(m2[t], hi);
                }
        }
    }

    // cross-column reduce within 16-lane groups
    #pragma unroll
    for (int off = 1; off < 16; off <<= 1) {
        #pragma unroll
        for (int t = 0; t < 8; ++t) {
            const unsigned o1 = __shfl_xor(m1[t], off, 64);
            const unsigned o2 = __shfl_xor(m2[t], off, 64);
            const unsigned nm2 = umin32(umin32(m2[t], o2), umax32(m1[t], o1));
            m1[t] = umin32(m1[t], o1);
            m2[t] = nm2;
        }
    }

    if (c == 0) {
        #pragma unroll
        for (int t = 0; t < 8; ++t) {
            const int row   = (t >> 2) * 16 + g * 4 + (t & 3);
            const int token = T0w + row;
            idxArr[token] = (int)(m1[t] & 1023u);
            if (((m2[t] >> 10) - (m1[t] >> 10)) < FLAG_THR) {
                const unsigned pos = atomicAdd(flagCnt, 1u);
                if (pos < FLAG_CAP) flagList[pos] = (unsigned)token;
            }
        }
    }
}

// ---------------- fixup: exact fp32 re-argmin, LDS-staged & coalesced ----------------
// grid 2048, 256 threads, 8 tokens/block/iter. thread = (f = tid&7, rloc = tid>>3).
#define FX_S 260   // padded fp32 row stride: 260%32=4 -> 8 consecutive rows hit distinct bank groups; 16B aligned
__global__ __launch_bounds__(256) void fixup_kernel(const float* __restrict__ x,
                                                    const float* __restrict__ emb,
                                                    const float* __restrict__ eNorm,
                                                    const unsigned* __restrict__ flagCnt,
                                                    const unsigned* __restrict__ flagList,
                                                    int* __restrict__ idxArr) {
    __shared__ float xs[8][FX_S];
    __shared__ float es[32][FX_S];
    __shared__ unsigned tok_s[8];
    __shared__ unsigned long long red[4][8];
    const unsigned nf = umin32(*flagCnt, (unsigned)FLAG_CAP);
    const int tid  = threadIdx.x;
    const int lane = tid & 63;
    const int wv   = tid >> 6;
    const int f    = tid & 7;
    const int rloc = tid >> 3;

    for (unsigned base = blockIdx.x * 8u; base < nf; base += gridDim.x * 8u) {
        const unsigned B = umin32(8u, nf - base);
        __syncthreads();
        if (tid < 8) tok_s[tid] = flagList[base + (tid < (int)B ? tid : 0)];
        __syncthreads();
        // stage 8 token rows, coalesced (512 float4)
        #pragma unroll
        for (int s = 0; s < 2; ++s) {
            const int fi = s * 256 + tid;
            const int fr = fi >> 6, q4 = fi & 63;
            const float4 v = *reinterpret_cast<const float4*>(
                x + (size_t)tok_s[fr] * DIM + q4 * 4);
            *reinterpret_cast<float4*>(&xs[fr][q4 * 4]) = v;
        }

        unsigned long long bestk = 0xFFFFFFFFFFFFFFFFull;

        for (int ch = 0; ch < 32; ++ch) {
            __syncthreads();
            // stage 32 emb rows, coalesced (2048 float4)
            #pragma unroll
            for (int s = 0; s < 8; ++s) {
                const int fi = s * 256 + tid;
                const int rr = fi >> 6, q4 = fi & 63;
                const float4 v = *reinterpret_cast<const float4*>(
                    emb + (size_t)(ch * 32 + rr) * DIM + q4 * 4);
                *reinterpret_cast<float4*>(&es[rr][q4 * 4]) = v;
            }
            __syncthreads();

            float a0 = 0.f, a1 = 0.f, a2 = 0.f, a3 = 0.f;
            #pragma unroll 8
            for (int k = 0; k < 64; ++k) {
                const float4 av = *reinterpret_cast<const float4*>(&xs[f][k * 4]);
                const float4 bv = *reinterpret_cast<const float4*>(&es[rloc][k * 4]);
                a0 = fmaf(av.x, bv.x, a0);
                a1 = fmaf(av.y, bv.y, a1);
                a2 = fmaf(av.z, bv.z, a2);
                a3 = fmaf(av.w, bv.w, a3);
            }
            const float dot = (a0 + a1) + (a2 + a3);
            const int   row = ch * 32 + rloc;
            const float d   = eNorm[row] - 2.0f * dot + 512.0f;   // > 0 always
            const unsigned long long key =
                (((unsigned long long)__builtin_bit_cast(unsigned, d)) << 10) |
                (unsigned long long)row;
            bestk = umin64(bestk, key);
        }

        // reduce across lanes sharing f (l = f mod 8): offsets 8,16,32
        bestk = umin64(bestk, __shfl_xor(bestk, 8, 64));
        bestk = umin64(bestk, __shfl_xor(bestk, 16, 64));
        bestk = umin64(bestk, __shfl_xor(bestk, 32, 64));
        if (lane < 8) red[wv][lane] = bestk;
        __syncthreads();
        if (tid < (int)B) {
            const unsigned long long m = umin64(umin64(red[0][tid], red[1][tid]),
                                                umin64(red[2][tid], red[3][tid]));
            idxArr[tok_s[tid]] = (int)(m & 1023ull);
        }
    }
}

// ---------------- gather + histogram ----------------
__global__ __launch_bounds__(256) void gather_hist(const float* __restrict__ emb,
                                                   const int* __restrict__ idxArr,
                                                   unsigned* __restrict__ counts,
                                                   float* __restrict__ out) {
    __shared__ int idx_s[256];
    const int tid = threadIdx.x;
    const int T0  = blockIdx.x * 256;
    const int e   = idxArr[T0 + tid];
    idx_s[tid] = e;
    atomicAdd(&counts[e], 1u);
    __syncthreads();
    #pragma unroll 4
    for (int s = 0; s < 64; ++s) {
        const int fi  = s * 256 + tid;
        const int row = fi >> 6;
        const int q4  = fi & 63;
        const int em  = idx_s[row];
        *reinterpret_cast<float4*>(out + (size_t)(T0 + row) * DIM + q4 * 4) =
            *reinterpret_cast<const float4*>(emb + (size_t)em * DIM + q4 * 4);
    }
}

// ---------------- perplexity ----------------
__global__ __launch_bounds__(256) void perp_kernel(const unsigned* __restrict__ counts,
                                                   float* __restrict__ out_perp) {
    __shared__ float red[256];
    const int tid = threadIdx.x;
    float s = 0.0f;
    for (int i = tid; i < KEMB; i += 256) {
        const float p = (float)counts[i] / (float)NTOK;
        s += p * logf(p + 1e-10f);
    }
    red[tid] = s;
    __syncthreads();
    for (int off = 128; off; off >>= 1) {
        if (tid < off) red[tid] += red[tid + off];
        __syncthreads();
    }
    if (tid == 0) *out_perp = expf(-red[0]);
}

extern "C" void kernel_launch(void* const* d_in, const int* in_sizes, int n_in,
                              void* d_out, int out_size, void* d_ws, size_t ws_size,
                              hipStream_t stream) {
    (void)in_sizes; (void)n_in; (void)out_size; (void)ws_size;
    const float* x   = (const float*)d_in[0];
    const float* emb = (const float*)d_in[1];
    float* out = (float*)d_out;

    char* ws = (char*)d_ws;
    float*    eNorm    = (float*)(ws);
    float*    eConst   = (float*)(ws + 4096);
    unsigned* counts   = (unsigned*)(ws + 8192);
    unsigned* flagCnt  = (unsigned*)(ws + 12288);
    unsigned* flagList = (unsigned*)(ws + 16384);
    int*      idxArr   = (int*)(ws + 16384 + FLAG_CAP * 4);

    prep_kernel<<<KEMB, 64, 0, stream>>>(emb, eNorm, eConst, counts, flagCnt);
    vq_main<<<NTOK / 128, 256, 0, stream>>>(x, emb, eConst, idxArr, flagCnt, flagList);
    fixup_kernel<<<2048, 256, 0, stream>>>(x, emb, eNorm, flagCnt, flagList, idxArr);
    gather_hist<<<NTOK / 256, 256, 0, stream>>>(emb, idxArr, counts, out);
    perp_kernel<<<1, 256, 0, stream>>>(counts, out + (size_t)NTOK * DIM);
}

// Round 5
// 435.476 us; speedup vs baseline: 4.3154x; 1.1267x over previous
//
#include <hip/hip_runtime.h>
#include <math.h>
#include <stdint.h>

#define NTOK 131072
#define DIM  256
#define KEMB 1024

typedef _Float16 f16x8 __attribute__((ext_vector_type(8)));
typedef float    f32x4 __attribute__((ext_vector_type(4)));

#define FLAG_CAP 65536
#define FLAG_THR 16u   // key-prefix units; guarantees flagging any true gap < 0.5

static __device__ __forceinline__ unsigned umin32(unsigned a, unsigned b){ return a<b?a:b; }
static __device__ __forceinline__ unsigned umax32(unsigned a, unsigned b){ return a>b?a:b; }
static __device__ __forceinline__ unsigned long long umin64(unsigned long long a, unsigned long long b){ return a<b?a:b; }

static __device__ __forceinline__ void gload_lds16(const void* g, void* l) {
    __builtin_amdgcn_global_load_lds(
        (const __attribute__((address_space(1))) unsigned int*)g,
        (__attribute__((address_space(3))) unsigned int*)l, 16, 0, 0);
}

// ---------------- prep: norms, cst2, zero counters, pre-swizzled fp16 codebook image ----
// img layout: byte offset k*512 + p*16 holds emb[k][ (p^(k&7))*8 .. +7 ] as fp16.
// vq_main copies this linearly into LDS; ds_read at slot s then reads position s^(r&7). 
__global__ __launch_bounds__(64) void prep_kernel(const float* __restrict__ emb,
                                                  float* __restrict__ eNorm,
                                                  float* __restrict__ cst2,
                                                  unsigned* __restrict__ counts,
                                                  unsigned* __restrict__ flagCnt,
                                                  _Float16* __restrict__ img) {
    const int k = blockIdx.x;
    const int lane = threadIdx.x;
    const float4 v = *reinterpret_cast<const float4*>(emb + (size_t)k * DIM + lane * 4);
    float s = v.x * v.x + v.y * v.y + v.z * v.z + v.w * v.w;
    #pragma unroll
    for (int m = 32; m; m >>= 1) s += __shfl_xor(s, m, 64);
    if (lane == 0) {
        eNorm[k] = s;
        cst2[k]  = s + 512.0f;       // d = cst2 - 2*dot = dist - ||x||^2 + 512 > 0
        counts[k] = 0u;
        if (k == 0) *flagCnt = 0u;
    }
    if (lane < 32) {
        const int p = lane;
        const int sl = p ^ (k & 7);
        const float4 f0 = *reinterpret_cast<const float4*>(emb + (size_t)k * DIM + sl * 8);
        const float4 f1 = *reinterpret_cast<const float4*>(emb + (size_t)k * DIM + sl * 8 + 4);
        f16x8 h = (f16x8){(_Float16)f0.x, (_Float16)f0.y, (_Float16)f0.z, (_Float16)f0.w,
                          (_Float16)f1.x, (_Float16)f1.y, (_Float16)f1.z, (_Float16)f1.w};
        *reinterpret_cast<f16x8*>(img + (size_t)k * 256 + p * 8) = h;
    }
}

// ---------------- main: fp16 MFMA + packed-key top2 + fused gather/hist ----------------
__global__ __launch_bounds__(256, 2) void vq_main(const float* __restrict__ x,
                                                  const float* __restrict__ emb,
                                                  const _Float16* __restrict__ img,
                                                  const float* __restrict__ cst2,
                                                  int* __restrict__ idxArr,
                                                  unsigned* __restrict__ counts,
                                                  unsigned* __restrict__ flagCnt,
                                                  unsigned* __restrict__ flagList,
                                                  float* __restrict__ out) {
    __shared__ _Float16 B[2][16384];   // 2 x 32KB chunk buffers (swizzled image)
    __shared__ float cst_s[1024];
    __shared__ int idx_s[128];

    const int tid  = threadIdx.x;
    const int wv   = tid >> 6;
    const int lane = tid & 63;
    const int g    = lane >> 4;
    const int c    = lane & 15;
    const int T0   = blockIdx.x * 128;
    const int T0w  = T0 + wv * 32;

    // stage all 1024 cst floats once
    *reinterpret_cast<float4*>(&cst_s[tid * 4]) =
        *reinterpret_cast<const float4*>(&cst2[tid * 4]);

    // issue stage of chunk 0 (identity copy, direct to LDS)
    #pragma unroll
    for (int i = 0; i < 8; ++i)
        gload_lds16((const char*)img + (i * 256 + tid) * 16,
                    (char*)&B[0][0] + i * 4096 + wv * 1024);

    // A fragments: x[token][k], token = T0w + i*16 + c, k = kk*32 + g*8 ..
    f16x8 a[2][8];
    #pragma unroll
    for (int i = 0; i < 2; ++i) {
        const float* xr = x + (size_t)(T0w + i * 16 + c) * DIM + g * 8;
        #pragma unroll
        for (int kk = 0; kk < 8; ++kk) {
            const float4 f0 = *reinterpret_cast<const float4*>(xr + kk * 32);
            const float4 f1 = *reinterpret_cast<const float4*>(xr + kk * 32 + 4);
            a[i][kk] = (f16x8){(_Float16)f0.x, (_Float16)f0.y, (_Float16)f0.z, (_Float16)f0.w,
                               (_Float16)f1.x, (_Float16)f1.y, (_Float16)f1.z, (_Float16)f1.w};
        }
    }

    unsigned m1[8], m2[8];
    #pragma unroll
    for (int t = 0; t < 8; ++t) { m1[t] = 0xFFFFFFFFu; m2[t] = 0xFFFFFFFFu; }

    __syncthreads();   // chunk 0 landed (implicit vmcnt drain), cst_s visible

    for (int ec = 0; ec < 16; ++ec) {
        // prefetch next chunk into other buffer; latency hides under this chunk's compute
        if (ec < 15) {
            const char* src = (const char*)img + (ec + 1) * 32768;
            char* dst = (char*)&B[(ec + 1) & 1][0];
            #pragma unroll
            for (int i = 0; i < 8; ++i)
                gload_lds16(src + (i * 256 + tid) * 16, dst + i * 4096 + wv * 1024);
        }

        const _Float16* Bc = &B[ec & 1][0];
        f32x4 acc[2][4];
        #pragma unroll
        for (int i = 0; i < 2; ++i)
            #pragma unroll
            for (int j = 0; j < 4; ++j) acc[i][j] = (f32x4){0.f, 0.f, 0.f, 0.f};

        #pragma unroll
        for (int kk = 0; kk < 8; ++kk) {
            f16x8 b[4];
            #pragma unroll
            for (int j = 0; j < 4; ++j) {
                const int row = j * 16 + c;
                const int s   = kk * 4 + g;
                b[j] = *reinterpret_cast<const f16x8*>(&Bc[row * 256 + ((s ^ (row & 7)) << 3)]);
            }
            #pragma unroll
            for (int i = 0; i < 2; ++i)
                #pragma unroll
                for (int j = 0; j < 4; ++j)
                    acc[i][j] = __builtin_amdgcn_mfma_f32_16x16x32_f16(a[i][kk], b[j], acc[i][j], 0, 0, 0);
        }

        // fold: key = (bits(d) & ~1023) | col  (d > 0 -> bits monotone in d)
        #pragma unroll
        for (int j = 0; j < 4; ++j) {
            const int      col = ec * 64 + j * 16 + c;
            const float    cst = cst_s[col];
            #pragma unroll
            for (int i = 0; i < 2; ++i)
                #pragma unroll
                for (int e = 0; e < 4; ++e) {
                    const float    d   = fmaf(acc[i][j][e], -2.0f, cst);
                    const unsigned key = (__builtin_bit_cast(unsigned, d) & 0xFFFFFC00u) | (unsigned)col;
                    const int t = i * 4 + e;
                    m2[t] = umin32(m2[t], umax32(key, m1[t]));
                    m1[t] = umin32(m1[t], key);
                }
        }
        __syncthreads();   // drains prefetch (vmcnt 0) + all waves done reading Bc
    }

    // reduce across the 16 c-lanes
    #pragma unroll
    for (int off = 1; off < 16; off <<= 1) {
        #pragma unroll
        for (int t = 0; t < 8; ++t) {
            const unsigned o1 = __shfl_xor(m1[t], off, 64);
            const unsigned o2 = __shfl_xor(m2[t], off, 64);
            const unsigned nm2 = umin32(umin32(m2[t], o2), umax32(m1[t], o1));
            m1[t] = umin32(m1[t], o1);
            m2[t] = nm2;
        }
    }

    if (c == 0) {
        #pragma unroll
        for (int t = 0; t < 8; ++t) {
            const int row = (t >> 2) * 16 + g * 4 + (t & 3);   // within wave's 32 tokens
            const int idx = (int)(m1[t] & 1023u);
            idx_s[wv * 32 + row] = idx;
            idxArr[T0w + row] = idx;
            atomicAdd(&counts[idx], 1u);
            if (((m2[t] >> 10) - (m1[t] >> 10)) < FLAG_THR) {
                const unsigned pos = atomicAdd(flagCnt, 1u);
                if (pos < FLAG_CAP) flagList[pos] = (unsigned)(T0w + row);
            }
        }
    }
    __syncthreads();

    // fused gather: out[token] = emb[idx]  (128 rows x 1KB, coalesced per wave)
    #pragma unroll 4
    for (int s = 0; s < 32; ++s) {
        const int fi  = s * 256 + tid;
        const int row = fi >> 6;
        const int q4  = fi & 63;
        const int em  = idx_s[row];
        *reinterpret_cast<float4*>(out + (size_t)(T0 + row) * DIM + q4 * 4) =
            *reinterpret_cast<const float4*>(emb + (size_t)em * DIM + q4 * 4);
    }
}

// ---------------- fixup: exact fp32 re-argmin + patch out/counts ----------------
#define FX_S 260
__global__ __launch_bounds__(256) void fixup_kernel(const float* __restrict__ x,
                                                    const float* __restrict__ emb,
                                                    const float* __restrict__ eNorm,
                                                    const unsigned* __restrict__ flagCnt,
                                                    const unsigned* __restrict__ flagList,
                                                    int* __restrict__ idxArr,
                                                    unsigned* __restrict__ counts,
                                                    float* __restrict__ out) {
    __shared__ float xs[8][FX_S];
    __shared__ float es[32][FX_S];
    __shared__ unsigned tok_s[8];
    __shared__ int nidx_s[8];
    __shared__ unsigned long long red[4][8];
    const unsigned nf = umin32(*flagCnt, (unsigned)FLAG_CAP);
    const int tid  = threadIdx.x;
    const int lane = tid & 63;
    const int wv   = tid >> 6;
    const int f    = tid & 7;
    const int rloc = tid >> 3;

    for (unsigned base = blockIdx.x * 8u; base < nf; base += gridDim.x * 8u) {
        const unsigned B = umin32(8u, nf - base);
        __syncthreads();
        if (tid < 8) tok_s[tid] = flagList[base + (tid < (int)B ? tid : 0)];
        __syncthreads();
        #pragma unroll
        for (int s = 0; s < 2; ++s) {
            const int fi = s * 256 + tid;
            const int fr = fi >> 6, q4 = fi & 63;
            *reinterpret_cast<float4*>(&xs[fr][q4 * 4]) =
                *reinterpret_cast<const float4*>(x + (size_t)tok_s[fr] * DIM + q4 * 4);
        }

        unsigned long long bestk = 0xFFFFFFFFFFFFFFFFull;
        for (int ch = 0; ch < 32; ++ch) {
            __syncthreads();
            #pragma unroll
            for (int s = 0; s < 8; ++s) {
                const int fi = s * 256 + tid;
                const int rr = fi >> 6, q4 = fi & 63;
                *reinterpret_cast<float4*>(&es[rr][q4 * 4]) =
                    *reinterpret_cast<const float4*>(emb + (size_t)(ch * 32 + rr) * DIM + q4 * 4);
            }
            __syncthreads();

            float a0 = 0.f, a1 = 0.f, a2 = 0.f, a3 = 0.f;
            #pragma unroll 8
            for (int k = 0; k < 64; ++k) {
                const float4 av = *reinterpret_cast<const float4*>(&xs[f][k * 4]);
                const float4 bv = *reinterpret_cast<const float4*>(&es[rloc][k * 4]);
                a0 = fmaf(av.x, bv.x, a0);
                a1 = fmaf(av.y, bv.y, a1);
                a2 = fmaf(av.z, bv.z, a2);
                a3 = fmaf(av.w, bv.w, a3);
            }
            const float dot = (a0 + a1) + (a2 + a3);
            const int   row = ch * 32 + rloc;
            const float d   = eNorm[row] - 2.0f * dot + 512.0f;
            const unsigned long long key =
                (((unsigned long long)__builtin_bit_cast(unsigned, d)) << 10) |
                (unsigned long long)row;
            bestk = umin64(bestk, key);
        }

        bestk = umin64(bestk, __shfl_xor(bestk, 8, 64));
        bestk = umin64(bestk, __shfl_xor(bestk, 16, 64));
        bestk = umin64(bestk, __shfl_xor(bestk, 32, 64));
        if (lane < 8) red[wv][lane] = bestk;
        __syncthreads();
        if (tid < (int)B) {
            const unsigned long long m = umin64(umin64(red[0][tid], red[1][tid]),
                                                umin64(red[2][tid], red[3][tid]));
            const int newIdx = (int)(m & 1023ull);
            const int tok    = (int)tok_s[tid];
            const int oldIdx = idxArr[tok];
            nidx_s[tid] = newIdx;
            if (newIdx != oldIdx) {
                idxArr[tok] = newIdx;
                atomicSub(&counts[oldIdx], 1u);
                atomicAdd(&counts[newIdx], 1u);
            }
        }
        __syncthreads();
        // rewrite out rows (idempotent when index unchanged)
        #pragma unroll
        for (int s = 0; s < 2; ++s) {
            const int fi = s * 256 + tid;
            const int fr = fi >> 6, q4 = fi & 63;
            if (fr < (int)B)
                *reinterpret_cast<float4*>(out + (size_t)tok_s[fr] * DIM + q4 * 4) =
                    *reinterpret_cast<const float4*>(emb + (size_t)nidx_s[fr] * DIM + q4 * 4);
        }
    }
}

// ---------------- perplexity ----------------
__global__ __launch_bounds__(256) void perp_kernel(const unsigned* __restrict__ counts,
                                                   float* __restrict__ out_perp) {
    __shared__ float red[256];
    const int tid = threadIdx.x;
    float s = 0.0f;
    for (int i = tid; i < KEMB; i += 256) {
        const float p = (float)counts[i] / (float)NTOK;
        s += p * logf(p + 1e-10f);
    }
    red[tid] = s;
    __syncthreads();
    for (int off = 128; off; off >>= 1) {
        if (tid < off) red[tid] += red[tid + off];
        __syncthreads();
    }
    if (tid == 0) *out_perp = expf(-red[0]);
}

extern "C" void kernel_launch(void* const* d_in, const int* in_sizes, int n_in,
                              void* d_out, int out_size, void* d_ws, size_t ws_size,
                              hipStream_t stream) {
    (void)in_sizes; (void)n_in; (void)out_size; (void)ws_size;
    const float* x   = (const float*)d_in[0];
    const float* emb = (const float*)d_in[1];
    float* out = (float*)d_out;

    char* ws = (char*)d_ws;
    float*     eNorm    = (float*)(ws);                         // 4KB
    float*     cst2     = (float*)(ws + 4096);                  // 4KB
    unsigned*  counts   = (unsigned*)(ws + 8192);               // 4KB
    unsigned*  flagCnt  = (unsigned*)(ws + 12288);              // 4KB
    unsigned*  flagList = (unsigned*)(ws + 16384);              // 256KB
    int*       idxArr   = (int*)(ws + 16384 + FLAG_CAP * 4);    // 512KB
    _Float16*  img      = (_Float16*)(ws + 16384 + FLAG_CAP * 4 + NTOK * 4);  // 512KB

    prep_kernel<<<KEMB, 64, 0, stream>>>(emb, eNorm, cst2, counts, flagCnt, img);
    vq_main<<<NTOK / 128, 256, 0, stream>>>(x, emb, img, cst2, idxArr, counts,
                                            flagCnt, flagList, out);
    fixup_kernel<<<2048, 256, 0, stream>>>(x, emb, eNorm, flagCnt, flagList,
                                           idxArr, counts, out);
    perp_kernel<<<1, 256, 0, stream>>>(counts, out + (size_t)NTOK * DIM);
}

// Round 6
// 211.215 us; speedup vs baseline: 8.8973x; 2.0618x over previous
//
#include <hip/hip_runtime.h>
#include <math.h>
#include <stdint.h>

#define NTOK 131072
#define DIM  256
#define KEMB 1024

typedef _Float16 f16x8 __attribute__((ext_vector_type(8)));
typedef float    f32x4 __attribute__((ext_vector_type(4)));

#define FLAG_CAP 65536
#define FLAG_THR 8u    // prefix units (>=0.0625 each) -> flags any gap < ~0.5

static __device__ __forceinline__ unsigned umin32(unsigned a, unsigned b){ return a<b?a:b; }
static __device__ __forceinline__ unsigned umax32(unsigned a, unsigned b){ return a>b?a:b; }

static __device__ __forceinline__ void gload_lds16(const void* g, void* l) {
    __builtin_amdgcn_global_load_lds(
        (const __attribute__((address_space(1))) unsigned int*)g,
        (__attribute__((address_space(3))) unsigned int*)l, 16, 0, 0);
}

static __device__ __forceinline__ void split_hl(const float4& f0, const float4& f1,
                                                f16x8& h, f16x8& l) {
    float v[8] = {f0.x, f0.y, f0.z, f0.w, f1.x, f1.y, f1.z, f1.w};
    #pragma unroll
    for (int e = 0; e < 8; ++e) {
        const _Float16 hi = (_Float16)v[e];
        h[e] = hi;
        l[e] = (_Float16)(v[e] - (float)hi);
    }
}

// ---------------- prep: norms, cst2, counters, pre-swizzled hi/lo fp16 codebook ----
// img layout: half index k*256 + p*8 holds emb[k][ (p^(k&7))*8 .. +7 ].
__global__ __launch_bounds__(64) void prep_kernel(const float* __restrict__ emb,
                                                  float* __restrict__ eNorm,
                                                  float* __restrict__ cst2,
                                                  unsigned* __restrict__ counts,
                                                  unsigned* __restrict__ flagCnt,
                                                  _Float16* __restrict__ img_hi,
                                                  _Float16* __restrict__ img_lo) {
    const int k = blockIdx.x;
    const int lane = threadIdx.x;
    const float4 v = *reinterpret_cast<const float4*>(emb + (size_t)k * DIM + lane * 4);
    float s = v.x * v.x + v.y * v.y + v.z * v.z + v.w * v.w;
    #pragma unroll
    for (int m = 32; m; m >>= 1) s += __shfl_xor(s, m, 64);
    if (lane == 0) {
        eNorm[k] = s;
        cst2[k]  = s + 512.0f;       // d = cst2 - 2*dot > 0 always
        counts[k] = 0u;
        if (k == 0) *flagCnt = 0u;
    }
    if (lane < 32) {
        const int p = lane;
        const int sl = p ^ (k & 7);
        const float4 f0 = *reinterpret_cast<const float4*>(emb + (size_t)k * DIM + sl * 8);
        const float4 f1 = *reinterpret_cast<const float4*>(emb + (size_t)k * DIM + sl * 8 + 4);
        f16x8 h, l;
        split_hl(f0, f1, h, l);
        *reinterpret_cast<f16x8*>(img_hi + (size_t)k * 256 + p * 8) = h;
        *reinterpret_cast<f16x8*>(img_lo + (size_t)k * 256 + p * 8) = l;
    }
}

// ---------------- main: fp16 MFMA + packed-key top2 + fused gather/hist ----------------
__global__ __launch_bounds__(256, 2) void vq_main(const float* __restrict__ x,
                                                  const float* __restrict__ emb,
                                                  const _Float16* __restrict__ img,
                                                  const float* __restrict__ cst2,
                                                  int* __restrict__ idxArr,
                                                  unsigned* __restrict__ counts,
                                                  unsigned* __restrict__ flagCnt,
                                                  unsigned* __restrict__ flagList,
                                                  float* __restrict__ out) {
    __shared__ _Float16 B[2][16384];   // 2 x 32KB chunk buffers (swizzled image)
    __shared__ float cst_s[1024];
    __shared__ int idx_s[128];

    const int tid  = threadIdx.x;
    const int wv   = tid >> 6;
    const int lane = tid & 63;
    const int g    = lane >> 4;
    const int c    = lane & 15;
    const int T0   = blockIdx.x * 128;
    const int T0w  = T0 + wv * 32;

    *reinterpret_cast<float4*>(&cst_s[tid * 4]) =
        *reinterpret_cast<const float4*>(&cst2[tid * 4]);

    #pragma unroll
    for (int i = 0; i < 8; ++i)
        gload_lds16((const char*)img + (i * 256 + tid) * 16,
                    (char*)&B[0][0] + i * 4096 + wv * 1024);

    f16x8 a[2][8];
    #pragma unroll
    for (int i = 0; i < 2; ++i) {
        const float* xr = x + (size_t)(T0w + i * 16 + c) * DIM + g * 8;
        #pragma unroll
        for (int kk = 0; kk < 8; ++kk) {
            const float4 f0 = *reinterpret_cast<const float4*>(xr + kk * 32);
            const float4 f1 = *reinterpret_cast<const float4*>(xr + kk * 32 + 4);
            a[i][kk] = (f16x8){(_Float16)f0.x, (_Float16)f0.y, (_Float16)f0.z, (_Float16)f0.w,
                               (_Float16)f1.x, (_Float16)f1.y, (_Float16)f1.z, (_Float16)f1.w};
        }
    }

    unsigned m1[8], m2[8];
    #pragma unroll
    for (int t = 0; t < 8; ++t) { m1[t] = 0xFFFFFFFFu; m2[t] = 0xFFFFFFFFu; }

    __syncthreads();

    for (int ec = 0; ec < 16; ++ec) {
        if (ec < 15) {
            const char* src = (const char*)img + (ec + 1) * 32768;
            char* dst = (char*)&B[(ec + 1) & 1][0];
            #pragma unroll
            for (int i = 0; i < 8; ++i)
                gload_lds16(src + (i * 256 + tid) * 16, dst + i * 4096 + wv * 1024);
        }

        const _Float16* Bc = &B[ec & 1][0];
        f32x4 acc[2][4];
        #pragma unroll
        for (int i = 0; i < 2; ++i)
            #pragma unroll
            for (int j = 0; j < 4; ++j) acc[i][j] = (f32x4){0.f, 0.f, 0.f, 0.f};

        #pragma unroll
        for (int kk = 0; kk < 8; ++kk) {
            f16x8 b[4];
            #pragma unroll
            for (int j = 0; j < 4; ++j) {
                const int row = j * 16 + c;
                const int s   = kk * 4 + g;
                b[j] = *reinterpret_cast<const f16x8*>(&Bc[row * 256 + ((s ^ (row & 7)) << 3)]);
            }
            #pragma unroll
            for (int i = 0; i < 2; ++i)
                #pragma unroll
                for (int j = 0; j < 4; ++j)
                    acc[i][j] = __builtin_amdgcn_mfma_f32_16x16x32_f16(a[i][kk], b[j], acc[i][j], 0, 0, 0);
        }

        #pragma unroll
        for (int j = 0; j < 4; ++j) {
            const int   col = ec * 64 + j * 16 + c;
            const float cst = cst_s[col];
            #pragma unroll
            for (int i = 0; i < 2; ++i)
                #pragma unroll
                for (int e = 0; e < 4; ++e) {
                    const float    d   = fmaf(acc[i][j][e], -2.0f, cst);
                    const unsigned key = (__builtin_bit_cast(unsigned, d) & 0xFFFFFC00u) | (unsigned)col;
                    const int t = i * 4 + e;
                    m2[t] = umin32(m2[t], umax32(key, m1[t]));
                    m1[t] = umin32(m1[t], key);
                }
        }
        __syncthreads();
    }

    #pragma unroll
    for (int off = 1; off < 16; off <<= 1) {
        #pragma unroll
        for (int t = 0; t < 8; ++t) {
            const unsigned o1 = __shfl_xor(m1[t], off, 64);
            const unsigned o2 = __shfl_xor(m2[t], off, 64);
            const unsigned nm2 = umin32(umin32(m2[t], o2), umax32(m1[t], o1));
            m1[t] = umin32(m1[t], o1);
            m2[t] = nm2;
        }
    }

    if (c == 0) {
        #pragma unroll
        for (int t = 0; t < 8; ++t) {
            const int row = (t >> 2) * 16 + g * 4 + (t & 3);
            const int idx = (int)(m1[t] & 1023u);
            idx_s[wv * 32 + row] = idx;
            idxArr[T0w + row] = idx;
            atomicAdd(&counts[idx], 1u);
            if (((m2[t] >> 10) - (m1[t] >> 10)) < FLAG_THR) {
                const unsigned pos = atomicAdd(flagCnt, 1u);
                if (pos < FLAG_CAP) flagList[pos] = (unsigned)(T0w + row);
            }
        }
    }
    __syncthreads();

    #pragma unroll 4
    for (int s = 0; s < 32; ++s) {
        const int fi  = s * 256 + tid;
        const int row = fi >> 6;
        const int q4  = fi & 63;
        const int em  = idx_s[row];
        *reinterpret_cast<float4*>(out + (size_t)(T0 + row) * DIM + q4 * 4) =
            *reinterpret_cast<const float4*>(emb + (size_t)em * DIM + q4 * 4);
    }
}

// ---------------- fixup stage A: hi/lo-split 3-MFMA full rescan -> refined top-2 ----
// grid 1024 blocks x 4 waves, 16 tokens/wave: covers FLAG_CAP in one pass.
__global__ __launch_bounds__(256) void fixup_refine(const float* __restrict__ x,
                                                    const _Float16* __restrict__ img_hi,
                                                    const _Float16* __restrict__ img_lo,
                                                    const float* __restrict__ cst2,
                                                    const unsigned* __restrict__ flagCnt,
                                                    const unsigned* __restrict__ flagList,
                                                    uint2* __restrict__ refTop) {
    __shared__ _Float16 Bh[16384];
    __shared__ _Float16 Bl[16384];
    __shared__ float cst_s[1024];

    const unsigned nf = umin32(*flagCnt, (unsigned)FLAG_CAP);
    if (blockIdx.x * 64u >= nf) return;   // uniform early exit

    const int tid  = threadIdx.x;
    const int wv   = tid >> 6;
    const int lane = tid & 63;
    const int g    = lane >> 4;
    const int c    = lane & 15;
    const unsigned base = (blockIdx.x * 4u + (unsigned)wv) * 16u;

    *reinterpret_cast<float4*>(&cst_s[tid * 4]) =
        *reinterpret_cast<const float4*>(&cst2[tid * 4]);

    // gather A hi/lo frags for this lane's token (row = c)
    const unsigned myTok = flagList[(base + c) < nf ? (base + c) : 0];
    f16x8 ah[8], al[8];
    {
        const float* xr = x + (size_t)myTok * DIM + g * 8;
        #pragma unroll
        for (int kk = 0; kk < 8; ++kk) {
            const float4 f0 = *reinterpret_cast<const float4*>(xr + kk * 32);
            const float4 f1 = *reinterpret_cast<const float4*>(xr + kk * 32 + 4);
            split_hl(f0, f1, ah[kk], al[kk]);
        }
    }

    unsigned m1[4], m2[4];
    #pragma unroll
    for (int e = 0; e < 4; ++e) { m1[e] = 0xFFFFFFFFu; m2[e] = 0xFFFFFFFFu; }

    for (int ec = 0; ec < 16; ++ec) {
        __syncthreads();
        #pragma unroll
        for (int i = 0; i < 8; ++i) {
            gload_lds16((const char*)img_hi + ec * 32768 + (i * 256 + tid) * 16,
                        (char*)&Bh[0] + i * 4096 + wv * 1024);
            gload_lds16((const char*)img_lo + ec * 32768 + (i * 256 + tid) * 16,
                        (char*)&Bl[0] + i * 4096 + wv * 1024);
        }
        __syncthreads();

        f32x4 acc[4];
        #pragma unroll
        for (int j = 0; j < 4; ++j) acc[j] = (f32x4){0.f, 0.f, 0.f, 0.f};

        #pragma unroll
        for (int kk = 0; kk < 8; ++kk) {
            #pragma unroll
            for (int j = 0; j < 4; ++j) {
                const int row = j * 16 + c;
                const int off = row * 256 + (((kk * 4 + g) ^ (row & 7)) << 3);
                const f16x8 bh = *reinterpret_cast<const f16x8*>(&Bh[off]);
                const f16x8 bl = *reinterpret_cast<const f16x8*>(&Bl[off]);
                acc[j] = __builtin_amdgcn_mfma_f32_16x16x32_f16(ah[kk], bh, acc[j], 0, 0, 0);
                acc[j] = __builtin_amdgcn_mfma_f32_16x16x32_f16(ah[kk], bl, acc[j], 0, 0, 0);
                acc[j] = __builtin_amdgcn_mfma_f32_16x16x32_f16(al[kk], bh, acc[j], 0, 0, 0);
            }
        }

        #pragma unroll
        for (int j = 0; j < 4; ++j) {
            const int   col = ec * 64 + j * 16 + c;
            const float cst = cst_s[col];
            #pragma unroll
            for (int e = 0; e < 4; ++e) {
                const float    d   = fmaf(acc[j][e], -2.0f, cst);
                const unsigned key = (__builtin_bit_cast(unsigned, d) & 0xFFFFFC00u) | (unsigned)col;
                m2[e] = umin32(m2[e], umax32(key, m1[e]));
                m1[e] = umin32(m1[e], key);
            }
        }
    }

    #pragma unroll
    for (int off = 1; off < 16; off <<= 1) {
        #pragma unroll
        for (int e = 0; e < 4; ++e) {
            const unsigned o1 = __shfl_xor(m1[e], off, 64);
            const unsigned o2 = __shfl_xor(m2[e], off, 64);
            const unsigned nm2 = umin32(umin32(m2[e], o2), umax32(m1[e], o1));
            m1[e] = umin32(m1[e], o1);
            m2[e] = nm2;
        }
    }

    if (c == 0) {
        #pragma unroll
        for (int e = 0; e < 4; ++e) {
            const unsigned pos = base + (unsigned)(g * 4 + e);
            if (pos < nf) refTop[pos] = make_uint2(m1[e], m2[e]);
        }
    }
}

// ---------------- fixup stage B: exact fp32 compare of refined top-2, patch ----------
__global__ __launch_bounds__(256) void fixup_exact(const float* __restrict__ x,
                                                   const float* __restrict__ emb,
                                                   const float* __restrict__ eNorm,
                                                   const unsigned* __restrict__ flagCnt,
                                                   const unsigned* __restrict__ flagList,
                                                   const uint2* __restrict__ refTop,
                                                   int* __restrict__ idxArr,
                                                   unsigned* __restrict__ counts,
                                                   float* __restrict__ out) {
    const unsigned nf = umin32(*flagCnt, (unsigned)FLAG_CAP);
    const int tid  = threadIdx.x;
    const int wv   = tid >> 6;
    const int lane = tid & 63;

    for (unsigned pos = blockIdx.x * 4u + (unsigned)wv; pos < nf; pos += gridDim.x * 4u) {
        const unsigned tok = flagList[pos];
        const uint2 tk = refTop[pos];
        const int e1 = (int)(tk.x & 1023u);
        const int e2 = (int)(tk.y & 1023u);

        const float4 xv = *reinterpret_cast<const float4*>(x   + (size_t)tok * DIM + lane * 4);
        const float4 v1 = *reinterpret_cast<const float4*>(emb + (size_t)e1  * DIM + lane * 4);
        const float4 v2 = *reinterpret_cast<const float4*>(emb + (size_t)e2  * DIM + lane * 4);
        float p1 = xv.x * v1.x + xv.y * v1.y + xv.z * v1.z + xv.w * v1.w;
        float p2 = xv.x * v2.x + xv.y * v2.y + xv.z * v2.z + xv.w * v2.w;
        #pragma unroll
        for (int off = 1; off < 64; off <<= 1) {
            p1 += __shfl_xor(p1, off, 64);
            p2 += __shfl_xor(p2, off, 64);
        }
        const float d1 = eNorm[e1] - 2.0f * p1;
        const float d2 = eNorm[e2] - 2.0f * p2;
        const bool pick2 = (d2 < d1) || (d2 == d1 && e2 < e1);
        const int  ni   = pick2 ? e2 : e1;
        const int  old  = idxArr[tok];
        if (ni != old) {
            if (lane == 0) {
                idxArr[tok] = ni;
                atomicSub(&counts[old], 1u);
                atomicAdd(&counts[ni], 1u);
            }
            const float4 nv = pick2 ? v2 : v1;
            *reinterpret_cast<float4*>(out + (size_t)tok * DIM + lane * 4) = nv;
        }
    }
}

// ---------------- perplexity ----------------
__global__ __launch_bounds__(256) void perp_kernel(const unsigned* __restrict__ counts,
                                                   float* __restrict__ out_perp) {
    __shared__ float red[256];
    const int tid = threadIdx.x;
    float s = 0.0f;
    for (int i = tid; i < KEMB; i += 256) {
        const float p = (float)counts[i] / (float)NTOK;
        s += p * logf(p + 1e-10f);
    }
    red[tid] = s;
    __syncthreads();
    for (int off = 128; off; off >>= 1) {
        if (tid < off) red[tid] += red[tid + off];
        __syncthreads();
    }
    if (tid == 0) *out_perp = expf(-red[0]);
}

extern "C" void kernel_launch(void* const* d_in, const int* in_sizes, int n_in,
                              void* d_out, int out_size, void* d_ws, size_t ws_size,
                              hipStream_t stream) {
    (void)in_sizes; (void)n_in; (void)out_size; (void)ws_size;
    const float* x   = (const float*)d_in[0];
    const float* emb = (const float*)d_in[1];
    float* out = (float*)d_out;

    char* ws = (char*)d_ws;
    float*     eNorm    = (float*)(ws);                          // 4KB
    float*     cst2     = (float*)(ws + 4096);                   // 4KB
    unsigned*  counts   = (unsigned*)(ws + 8192);                // 4KB
    unsigned*  flagCnt  = (unsigned*)(ws + 12288);               // 4KB
    unsigned*  flagList = (unsigned*)(ws + 16384);               // 256KB
    int*       idxArr   = (int*)(ws + 278528);                   // 512KB
    _Float16*  img_hi   = (_Float16*)(ws + 802816);              // 512KB
    _Float16*  img_lo   = (_Float16*)(ws + 1327104);             // 512KB
    uint2*     refTop   = (uint2*)(ws + 1851392);                // 512KB

    prep_kernel<<<KEMB, 64, 0, stream>>>(emb, eNorm, cst2, counts, flagCnt, img_hi, img_lo);
    vq_main<<<NTOK / 128, 256, 0, stream>>>(x, emb, img_hi, cst2, idxArr, counts,
                                            flagCnt, flagList, out);
    fixup_refine<<<1024, 256, 0, stream>>>(x, img_hi, img_lo, cst2, flagCnt, flagList, refTop);
    fixup_exact<<<2048, 256, 0, stream>>>(x, emb, eNorm, flagCnt, flagList, refTop,
                                          idxArr, counts, out);
    perp_kernel<<<1, 256, 0, stream>>>(counts, out + (size_t)NTOK * DIM);
}

// Round 7
// 203.558 us; speedup vs baseline: 9.2320x; 1.0376x over previous
//
#include <hip/hip_runtime.h>
#include <math.h>
#include <stdint.h>

#define NTOK 131072
#define DIM  256
#define KEMB 1024

typedef _Float16 f16x8 __attribute__((ext_vector_type(8)));
typedef float    f32x4 __attribute__((ext_vector_type(4)));

#define FLAG_CAP 65536
#define FLAG_THR 8u    // prefix units (>=0.0625 each) -> flags any gap < ~0.5

static __device__ __forceinline__ unsigned umin32(unsigned a, unsigned b){ return a<b?a:b; }
static __device__ __forceinline__ unsigned umax32(unsigned a, unsigned b){ return a>b?a:b; }

static __device__ __forceinline__ void gload_lds16(const void* g, void* l) {
    __builtin_amdgcn_global_load_lds(
        (const __attribute__((address_space(1))) unsigned int*)g,
        (__attribute__((address_space(3))) unsigned int*)l, 16, 0, 0);
}

static __device__ __forceinline__ void split_hl(const float4& f0, const float4& f1,
                                                f16x8& h, f16x8& l) {
    float v[8] = {f0.x, f0.y, f0.z, f0.w, f1.x, f1.y, f1.z, f1.w};
    #pragma unroll
    for (int e = 0; e < 8; ++e) {
        const _Float16 hi = (_Float16)v[e];
        h[e] = hi;
        l[e] = (_Float16)(v[e] - (float)hi);
    }
}

// ---------------- prep: norms, cst2, counters, pre-swizzled hi/lo fp16 codebook ----
// img layout: half index k*256 + p*8 holds emb[k][ (p^(k&7))*8 .. +7 ].
__global__ __launch_bounds__(64) void prep_kernel(const float* __restrict__ emb,
                                                  float* __restrict__ eNorm,
                                                  float* __restrict__ cst2,
                                                  unsigned* __restrict__ counts,
                                                  unsigned* __restrict__ flagCnt,
                                                  _Float16* __restrict__ img_hi,
                                                  _Float16* __restrict__ img_lo) {
    const int k = blockIdx.x;
    const int lane = threadIdx.x;
    const float4 v = *reinterpret_cast<const float4*>(emb + (size_t)k * DIM + lane * 4);
    float s = v.x * v.x + v.y * v.y + v.z * v.z + v.w * v.w;
    #pragma unroll
    for (int m = 32; m; m >>= 1) s += __shfl_xor(s, m, 64);
    if (lane == 0) {
        eNorm[k] = s;
        cst2[k]  = s + 512.0f;       // d = cst2 - 2*dot > 0 always
        counts[k] = 0u;
        if (k == 0) *flagCnt = 0u;
    }
    if (lane < 32) {
        const int p = lane;
        const int sl = p ^ (k & 7);
        const float4 f0 = *reinterpret_cast<const float4*>(emb + (size_t)k * DIM + sl * 8);
        const float4 f1 = *reinterpret_cast<const float4*>(emb + (size_t)k * DIM + sl * 8 + 4);
        f16x8 h, l;
        split_hl(f0, f1, h, l);
        *reinterpret_cast<f16x8*>(img_hi + (size_t)k * 256 + p * 8) = h;
        *reinterpret_cast<f16x8*>(img_lo + (size_t)k * 256 + p * 8) = l;
    }
}

// ---------------- main: fp16 MFMA + packed-key top2 + fused gather/hist ----------------
// 32-row chunks (16KB), double-buffered: LDS ~36.5KB -> 4 blocks/CU, grid co-resident.
__global__ __launch_bounds__(256, 4) void vq_main(const float* __restrict__ x,
                                                  const float* __restrict__ emb,
                                                  const _Float16* __restrict__ img,
                                                  const float* __restrict__ cst2,
                                                  int* __restrict__ idxArr,
                                                  unsigned* __restrict__ counts,
                                                  unsigned* __restrict__ flagCnt,
                                                  unsigned* __restrict__ flagList,
                                                  float* __restrict__ out) {
    __shared__ _Float16 B[2][8192];    // 2 x 16KB chunk buffers (swizzled image, 32 rows)
    __shared__ float cst_s[1024];
    __shared__ int idx_s[128];

    const int tid  = threadIdx.x;
    const int wv   = tid >> 6;
    const int lane = tid & 63;
    const int g    = lane >> 4;
    const int c    = lane & 15;
    const int T0   = blockIdx.x * 128;
    const int T0w  = T0 + wv * 32;

    *reinterpret_cast<float4*>(&cst_s[tid * 4]) =
        *reinterpret_cast<const float4*>(&cst2[tid * 4]);

    // stage chunk 0 (16KB: 4 passes x 4KB)
    #pragma unroll
    for (int i = 0; i < 4; ++i)
        gload_lds16((const char*)img + (i * 256 + tid) * 16,
                    (char*)&B[0][0] + i * 4096 + wv * 1024);

    // A fragments: x[token][k], token = T0w + i*16 + c, k = kk*32 + g*8 ..
    f16x8 a[2][8];
    #pragma unroll
    for (int i = 0; i < 2; ++i) {
        const float* xr = x + (size_t)(T0w + i * 16 + c) * DIM + g * 8;
        #pragma unroll
        for (int kk = 0; kk < 8; ++kk) {
            const float4 f0 = *reinterpret_cast<const float4*>(xr + kk * 32);
            const float4 f1 = *reinterpret_cast<const float4*>(xr + kk * 32 + 4);
            a[i][kk] = (f16x8){(_Float16)f0.x, (_Float16)f0.y, (_Float16)f0.z, (_Float16)f0.w,
                               (_Float16)f1.x, (_Float16)f1.y, (_Float16)f1.z, (_Float16)f1.w};
        }
    }

    unsigned m1[8], m2[8];
    #pragma unroll
    for (int t = 0; t < 8; ++t) { m1[t] = 0xFFFFFFFFu; m2[t] = 0xFFFFFFFFu; }

    __syncthreads();

    for (int ec = 0; ec < 32; ++ec) {
        if (ec < 31) {
            const char* src = (const char*)img + (ec + 1) * 16384;
            char* dst = (char*)&B[(ec + 1) & 1][0];
            #pragma unroll
            for (int i = 0; i < 4; ++i)
                gload_lds16(src + (i * 256 + tid) * 16, dst + i * 4096 + wv * 1024);
        }

        const _Float16* Bc = &B[ec & 1][0];
        f32x4 acc[2][2];
        #pragma unroll
        for (int i = 0; i < 2; ++i)
            #pragma unroll
            for (int j = 0; j < 2; ++j) acc[i][j] = (f32x4){0.f, 0.f, 0.f, 0.f};

        #pragma unroll
        for (int kk = 0; kk < 8; ++kk) {
            f16x8 b[2];
            #pragma unroll
            for (int j = 0; j < 2; ++j) {
                const int row = j * 16 + c;
                const int s   = kk * 4 + g;
                b[j] = *reinterpret_cast<const f16x8*>(&Bc[row * 256 + ((s ^ (row & 7)) << 3)]);
            }
            #pragma unroll
            for (int i = 0; i < 2; ++i)
                #pragma unroll
                for (int j = 0; j < 2; ++j)
                    acc[i][j] = __builtin_amdgcn_mfma_f32_16x16x32_f16(a[i][kk], b[j], acc[i][j], 0, 0, 0);
        }

        // fold: key = (bits(d) & ~1023) | col  (d > 0 -> bits monotone in d)
        #pragma unroll
        for (int j = 0; j < 2; ++j) {
            const int   col = ec * 32 + j * 16 + c;
            const float cst = cst_s[col];
            #pragma unroll
            for (int i = 0; i < 2; ++i)
                #pragma unroll
                for (int e = 0; e < 4; ++e) {
                    const float    d   = fmaf(acc[i][j][e], -2.0f, cst);
                    const unsigned key = (__builtin_bit_cast(unsigned, d) & 0xFFFFFC00u) | (unsigned)col;
                    const int t = i * 4 + e;
                    m2[t] = umin32(m2[t], umax32(key, m1[t]));
                    m1[t] = umin32(m1[t], key);
                }
        }
        __syncthreads();
    }

    #pragma unroll
    for (int off = 1; off < 16; off <<= 1) {
        #pragma unroll
        for (int t = 0; t < 8; ++t) {
            const unsigned o1 = __shfl_xor(m1[t], off, 64);
            const unsigned o2 = __shfl_xor(m2[t], off, 64);
            const unsigned nm2 = umin32(umin32(m2[t], o2), umax32(m1[t], o1));
            m1[t] = umin32(m1[t], o1);
            m2[t] = nm2;
        }
    }

    if (c == 0) {
        #pragma unroll
        for (int t = 0; t < 8; ++t) {
            const int row = (t >> 2) * 16 + g * 4 + (t & 3);
            const int idx = (int)(m1[t] & 1023u);
            idx_s[wv * 32 + row] = idx;
            idxArr[T0w + row] = idx;
            atomicAdd(&counts[idx], 1u);
            if (((m2[t] >> 10) - (m1[t] >> 10)) < FLAG_THR) {
                const unsigned pos = atomicAdd(flagCnt, 1u);
                if (pos < FLAG_CAP) flagList[pos] = (unsigned)(T0w + row);
            }
        }
    }
    __syncthreads();

    // fused gather: out[token] = emb[idx]
    #pragma unroll 4
    for (int s = 0; s < 32; ++s) {
        const int fi  = s * 256 + tid;
        const int row = fi >> 6;
        const int q4  = fi & 63;
        const int em  = idx_s[row];
        *reinterpret_cast<float4*>(out + (size_t)(T0 + row) * DIM + q4 * 4) =
            *reinterpret_cast<const float4*>(emb + (size_t)em * DIM + q4 * 4);
    }
}

// ---------------- fixup stage A: hi/lo-split 3-MFMA full rescan -> refined top-2 ----
__global__ __launch_bounds__(256) void fixup_refine(const float* __restrict__ x,
                                                    const _Float16* __restrict__ img_hi,
                                                    const _Float16* __restrict__ img_lo,
                                                    const float* __restrict__ cst2,
                                                    const unsigned* __restrict__ flagCnt,
                                                    const unsigned* __restrict__ flagList,
                                                    uint2* __restrict__ refTop) {
    __shared__ _Float16 Bh[16384];
    __shared__ _Float16 Bl[16384];
    __shared__ float cst_s[1024];

    const unsigned nf = umin32(*flagCnt, (unsigned)FLAG_CAP);
    if (blockIdx.x * 64u >= nf) return;

    const int tid  = threadIdx.x;
    const int wv   = tid >> 6;
    const int lane = tid & 63;
    const int g    = lane >> 4;
    const int c    = lane & 15;
    const unsigned base = (blockIdx.x * 4u + (unsigned)wv) * 16u;

    *reinterpret_cast<float4*>(&cst_s[tid * 4]) =
        *reinterpret_cast<const float4*>(&cst2[tid * 4]);

    const unsigned myTok = flagList[(base + c) < nf ? (base + c) : 0];
    f16x8 ah[8], al[8];
    {
        const float* xr = x + (size_t)myTok * DIM + g * 8;
        #pragma unroll
        for (int kk = 0; kk < 8; ++kk) {
            const float4 f0 = *reinterpret_cast<const float4*>(xr + kk * 32);
            const float4 f1 = *reinterpret_cast<const float4*>(xr + kk * 32 + 4);
            split_hl(f0, f1, ah[kk], al[kk]);
        }
    }

    unsigned m1[4], m2[4];
    #pragma unroll
    for (int e = 0; e < 4; ++e) { m1[e] = 0xFFFFFFFFu; m2[e] = 0xFFFFFFFFu; }

    for (int ec = 0; ec < 16; ++ec) {
        __syncthreads();
        #pragma unroll
        for (int i = 0; i < 8; ++i) {
            gload_lds16((const char*)img_hi + ec * 32768 + (i * 256 + tid) * 16,
                        (char*)&Bh[0] + i * 4096 + wv * 1024);
            gload_lds16((const char*)img_lo + ec * 32768 + (i * 256 + tid) * 16,
                        (char*)&Bl[0] + i * 4096 + wv * 1024);
        }
        __syncthreads();

        f32x4 acc[4];
        #pragma unroll
        for (int j = 0; j < 4; ++j) acc[j] = (f32x4){0.f, 0.f, 0.f, 0.f};

        #pragma unroll
        for (int kk = 0; kk < 8; ++kk) {
            #pragma unroll
            for (int j = 0; j < 4; ++j) {
                const int row = j * 16 + c;
                const int off = row * 256 + (((kk * 4 + g) ^ (row & 7)) << 3);
                const f16x8 bh = *reinterpret_cast<const f16x8*>(&Bh[off]);
                const f16x8 bl = *reinterpret_cast<const f16x8*>(&Bl[off]);
                acc[j] = __builtin_amdgcn_mfma_f32_16x16x32_f16(ah[kk], bh, acc[j], 0, 0, 0);
                acc[j] = __builtin_amdgcn_mfma_f32_16x16x32_f16(ah[kk], bl, acc[j], 0, 0, 0);
                acc[j] = __builtin_amdgcn_mfma_f32_16x16x32_f16(al[kk], bh, acc[j], 0, 0, 0);
            }
        }

        #pragma unroll
        for (int j = 0; j < 4; ++j) {
            const int   col = ec * 64 + j * 16 + c;
            const float cst = cst_s[col];
            #pragma unroll
            for (int e = 0; e < 4; ++e) {
                const float    d   = fmaf(acc[j][e], -2.0f, cst);
                const unsigned key = (__builtin_bit_cast(unsigned, d) & 0xFFFFFC00u) | (unsigned)col;
                m2[e] = umin32(m2[e], umax32(key, m1[e]));
                m1[e] = umin32(m1[e], key);
            }
        }
    }

    #pragma unroll
    for (int off = 1; off < 16; off <<= 1) {
        #pragma unroll
        for (int e = 0; e < 4; ++e) {
            const unsigned o1 = __shfl_xor(m1[e], off, 64);
            const unsigned o2 = __shfl_xor(m2[e], off, 64);
            const unsigned nm2 = umin32(umin32(m2[e], o2), umax32(m1[e], o1));
            m1[e] = umin32(m1[e], o1);
            m2[e] = nm2;
        }
    }

    if (c == 0) {
        #pragma unroll
        for (int e = 0; e < 4; ++e) {
            const unsigned pos = base + (unsigned)(g * 4 + e);
            if (pos < nf) refTop[pos] = make_uint2(m1[e], m2[e]);
        }
    }
}

// ---------------- fixup stage B: exact fp32 compare of refined top-2, patch ----------
__global__ __launch_bounds__(256) void fixup_exact(const float* __restrict__ x,
                                                   const float* __restrict__ emb,
                                                   const float* __restrict__ eNorm,
                                                   const unsigned* __restrict__ flagCnt,
                                                   const unsigned* __restrict__ flagList,
                                                   const uint2* __restrict__ refTop,
                                                   int* __restrict__ idxArr,
                                                   unsigned* __restrict__ counts,
                                                   float* __restrict__ out) {
    const unsigned nf = umin32(*flagCnt, (unsigned)FLAG_CAP);
    const int tid  = threadIdx.x;
    const int wv   = tid >> 6;
    const int lane = tid & 63;

    for (unsigned pos = blockIdx.x * 4u + (unsigned)wv; pos < nf; pos += gridDim.x * 4u) {
        const unsigned tok = flagList[pos];
        const uint2 tk = refTop[pos];
        const int e1 = (int)(tk.x & 1023u);
        const int e2 = (int)(tk.y & 1023u);

        const float4 xv = *reinterpret_cast<const float4*>(x   + (size_t)tok * DIM + lane * 4);
        const float4 v1 = *reinterpret_cast<const float4*>(emb + (size_t)e1  * DIM + lane * 4);
        const float4 v2 = *reinterpret_cast<const float4*>(emb + (size_t)e2  * DIM + lane * 4);
        float p1 = xv.x * v1.x + xv.y * v1.y + xv.z * v1.z + xv.w * v1.w;
        float p2 = xv.x * v2.x + xv.y * v2.y + xv.z * v2.z + xv.w * v2.w;
        #pragma unroll
        for (int off = 1; off < 64; off <<= 1) {
            p1 += __shfl_xor(p1, off, 64);
            p2 += __shfl_xor(p2, off, 64);
        }
        const float d1 = eNorm[e1] - 2.0f * p1;
        const float d2 = eNorm[e2] - 2.0f * p2;
        const bool pick2 = (d2 < d1) || (d2 == d1 && e2 < e1);
        const int  ni   = pick2 ? e2 : e1;
        const int  old  = idxArr[tok];
        if (ni != old) {
            if (lane == 0) {
                idxArr[tok] = ni;
                atomicSub(&counts[old], 1u);
                atomicAdd(&counts[ni], 1u);
            }
            const float4 nv = pick2 ? v2 : v1;
            *reinterpret_cast<float4*>(out + (size_t)tok * DIM + lane * 4) = nv;
        }
    }
}

// ---------------- perplexity ----------------
__global__ __launch_bounds__(256) void perp_kernel(const unsigned* __restrict__ counts,
                                                   float* __restrict__ out_perp) {
    __shared__ float red[256];
    const int tid = threadIdx.x;
    float s = 0.0f;
    for (int i = tid; i < KEMB; i += 256) {
        const float p = (float)counts[i] / (float)NTOK;
        s += p * logf(p + 1e-10f);
    }
    red[tid] = s;
    __syncthreads();
    for (int off = 128; off; off >>= 1) {
        if (tid < off) red[tid] += red[tid + off];
        __syncthreads();
    }
    if (tid == 0) *out_perp = expf(-red[0]);
}

extern "C" void kernel_launch(void* const* d_in, const int* in_sizes, int n_in,
                              void* d_out, int out_size, void* d_ws, size_t ws_size,
                              hipStream_t stream) {
    (void)in_sizes; (void)n_in; (void)out_size; (void)ws_size;
    const float* x   = (const float*)d_in[0];
    const float* emb = (const float*)d_in[1];
    float* out = (float*)d_out;

    char* ws = (char*)d_ws;
    float*     eNorm    = (float*)(ws);                          // 4KB
    float*     cst2     = (float*)(ws + 4096);                   // 4KB
    unsigned*  counts   = (unsigned*)(ws + 8192);                // 4KB
    unsigned*  flagCnt  = (unsigned*)(ws + 12288);               // 4KB
    unsigned*  flagList = (unsigned*)(ws + 16384);               // 256KB
    int*       idxArr   = (int*)(ws + 278528);                   // 512KB
    _Float16*  img_hi   = (_Float16*)(ws + 802816);              // 512KB
    _Float16*  img_lo   = (_Float16*)(ws + 1327104);             // 512KB
    uint2*     refTop   = (uint2*)(ws + 1851392);                // 512KB

    prep_kernel<<<KEMB, 64, 0, stream>>>(emb, eNorm, cst2, counts, flagCnt, img_hi, img_lo);
    vq_main<<<NTOK / 128, 256, 0, stream>>>(x, emb, img_hi, cst2, idxArr, counts,
                                            flagCnt, flagList, out);
    fixup_refine<<<1024, 256, 0, stream>>>(x, img_hi, img_lo, cst2, flagCnt, flagList, refTop);
    fixup_exact<<<2048, 256, 0, stream>>>(x, emb, eNorm, flagCnt, flagList, refTop,
                                          idxArr, counts, out);
    perp_kernel<<<1, 256, 0, stream>>>(counts, out + (size_t)NTOK * DIM);
}